// Round 6
// baseline (2128.479 us; speedup 1.0000x reference)
//
#include <hip/hip_runtime.h>
#include <hip/hip_bf16.h>
#include <stdint.h>

typedef __attribute__((ext_vector_type(4))) float f32x4;
typedef __attribute__((ext_vector_type(8))) short s16x8;
typedef unsigned short u16;

#define BM 128
#define BN 128
#define BK 32

// round-to-nearest-even f32 -> bf16 (bit pattern)
__device__ __forceinline__ u16 f32_to_bf16(float f) {
    uint32_t u = __float_as_uint(f);
    u = u + 0x7FFFu + ((u >> 16) & 1u);
    return (u16)(u >> 16);
}

// Transpose + convert: out[c*R + r] = bf16(in[r*C + c]).  R, C multiples of 32.
__global__ void stein_transpose_f32_bf16(const float* __restrict__ in,
                                         u16* __restrict__ out, int R, int C) {
    __shared__ float tile[32][33];
    const int tx = threadIdx.x, ty = threadIdx.y;     // 32 x 8
    const int c0 = blockIdx.x * 32, r0 = blockIdx.y * 32;
#pragma unroll
    for (int i = 0; i < 32; i += 8)
        tile[ty + i][tx] = in[(size_t)(r0 + ty + i) * C + (c0 + tx)];
    __syncthreads();
#pragma unroll
    for (int i = 0; i < 32; i += 8)
        out[(size_t)(c0 + ty + i) * R + (r0 + tx)] = f32_to_bf16(tile[tx][ty + i]);
}

// Straight convert f32 -> bf16, 4 elements/thread. n multiple of 4.
__global__ void stein_convert_f32_bf16(const float* __restrict__ in,
                                       u16* __restrict__ out, int n) {
    int i = (blockIdx.x * blockDim.x + threadIdx.x) * 4;
    if (i >= n) return;
    f32x4 v = *(const f32x4*)(in + i);
    uint2 u;
    u.x = (uint32_t)f32_to_bf16(v[0]) | ((uint32_t)f32_to_bf16(v[1]) << 16);
    u.y = (uint32_t)f32_to_bf16(v[2]) | ((uint32_t)f32_to_bf16(v[3]) << 16);
    *(uint2*)(out + i) = u;
}

// Runtime-descriptor GEMM op: C[m,n] = sum_k U[m,k] V[n,k]  (NT, bf16 in).
struct GemmOp {
    const u16* U; const u16* V;
    const float* Add;
    u16* OutB; u16* OutT; float* OutF;
    int K, ldu, ldv;
};

// grid (16,16,z) — blockIdx.z selects op0/op1. 128x128x32 tile, 4 waves,
// double-buffered LDS with REGISTER-STAGED depth-2 prefetch:
//   global_load_dwordx4 -> 4-deep VGPR ring -> ds_write_b128 -> LDS -> MFMA.
// Ring invariant: tile t lives in register set t&3.
//   prologue: sets 0..2 <- tiles 0..2
//   iter tk:  (a) stage tile tk+1 to LDS from set (tk+1)&3  [written iter tk-2]
//             (b) load tile tk+3 into set (tk+3)&3          [old tile tk-1,
//                                                            consumed iter tk-2]
//             (c) MFMA tile tk from LDS buf tk&1; __syncthreads (lgkm only —
//                 global loads stay in flight across the barrier).
// R5 BUG (fixed here): load dest was set tk&3, breaking the invariant from
// tile 3 onward (iter2 staged a never-written set). absmax 38.9 -> expect 0.5.
// LDS bank swizzle (R4): physical k-chunk p of row r holds logical chunk
// p ^ ((r>>1)&3); readers use kq = (lane>>4) ^ ((lane>>1)&3).
__global__ __launch_bounds__(256, 2) void stein_gemm_nt2(GemmOp op0, GemmOp op1) {
    const GemmOp op = (blockIdx.z == 0) ? op0 : op1;
    __shared__ alignas(16) short Us[2][BM * BK];
    __shared__ alignas(16) short Vs[2][BN * BK];

    const int t = threadIdx.x;
    const int wave = t >> 6;
    const int lane = t & 63;
    const int bm = blockIdx.x, bn = blockIdx.y;
    const int wm = (wave >> 1) * 64;
    const int wn = (wave & 1) * 64;

    // staging: wave w stages rows [w*16,w*16+16) and +64 of each tile.
    // lane l -> LDS slot (row=l>>2, phys chunk=l&3); source logical chunk
    // (l&3) ^ ((l>>3)&3).
    const int lrow = lane >> 2;
    const int lchunk = (lane & 3) ^ ((lane >> 3) & 3);
    const int lkof = lchunk * 8;
    const u16* gU0 = op.U + (size_t)(bm * BM + wave * 16 + lrow) * op.ldu + lkof;
    const u16* gU1 = gU0 + (size_t)64 * op.ldu;
    const u16* gV0 = op.V + (size_t)(bn * BN + wave * 16 + lrow) * op.ldv + lkof;
    const u16* gV1 = gV0 + (size_t)64 * op.ldv;
    const int su0 = (wave * 16) * BK;
    // LDS write addresses (bytes): wave chunk base + lane*16
    char* wUs[2], *wVs[2];
    wUs[0] = (char*)&Us[0][su0];
    wUs[1] = (char*)&Us[1][su0];
    wVs[0] = (char*)&Vs[0][su0];
    wVs[1] = (char*)&Vs[1][su0];
    const int loff = lane * 16;
    const int c2 = 64 * BK * 2;   // byte offset from su0 chunk to su1 chunk

    f32x4 acc[4][4];
#pragma unroll
    for (int i = 0; i < 4; ++i)
#pragma unroll
        for (int j = 0; j < 4; ++j) acc[i][j] = (f32x4){0.f, 0.f, 0.f, 0.f};

    const int arow = wm + (lane & 15);
    const int brow = wn + (lane & 15);
    const int kq = (lane >> 4) ^ ((lane >> 1) & 3);

    uint4 rU0[4], rU1[4], rV0[4], rV1[4];   // ring: tile t -> set t&3
    const int T = op.K / BK;                // T%4==0 (K=512 or 2048)

    // prologue: load tiles 0..2 into sets 0..2
#pragma unroll
    for (int pt = 0; pt < 3; ++pt) {
        const int kk = pt * BK;
        rU0[pt] = *(const uint4*)(gU0 + kk);
        rU1[pt] = *(const uint4*)(gU1 + kk);
        rV0[pt] = *(const uint4*)(gV0 + kk);
        rV1[pt] = *(const uint4*)(gV1 + kk);
    }
    // stage tile 0 into buf 0
    *(uint4*)(wUs[0] + loff) = rU0[0];
    *(uint4*)(wUs[0] + c2 + loff) = rU1[0];
    *(uint4*)(wVs[0] + loff) = rV0[0];
    *(uint4*)(wVs[0] + c2 + loff) = rV1[0];
    __syncthreads();

    for (int tg = 0; tg < T; tg += 4) {
#pragma unroll
        for (int u = 0; u < 4; ++u) {
            const int tk = tg + u;          // tk&3 == u, buf == u&1 (T%4==0)
            const int buf = u & 1;
            // a) stage tile tk+1 into buf^1 from set (u+1)&3
            if (tk + 1 < T) {
                const int s = (u + 1) & 3;
                *(uint4*)(wUs[buf ^ 1] + loff) = rU0[s];
                *(uint4*)(wUs[buf ^ 1] + c2 + loff) = rU1[s];
                *(uint4*)(wVs[buf ^ 1] + loff) = rV0[s];
                *(uint4*)(wVs[buf ^ 1] + c2 + loff) = rV1[s];
            }
            // b) issue loads for tile tk+3 into set (u+3)&3 (2-iter slack)
            if (tk + 3 < T) {
                const int d = (u + 3) & 3;          // FIX: was u (R5 bug)
                const int kk = (tk + 3) * BK;
                rU0[d] = *(const uint4*)(gU0 + kk);
                rU1[d] = *(const uint4*)(gU1 + kk);
                rV0[d] = *(const uint4*)(gV0 + kk);
                rV1[d] = *(const uint4*)(gV1 + kk);
            }
            // c) compute tile tk from buf
            s16x8 af[4], bfr[4];
#pragma unroll
            for (int i = 0; i < 4; ++i)
                af[i] = ((const s16x8*)Us[buf])[(arow + i * 16) * (BK / 8) + kq];
#pragma unroll
            for (int j = 0; j < 4; ++j)
                bfr[j] = ((const s16x8*)Vs[buf])[(brow + j * 16) * (BK / 8) + kq];
#pragma unroll
            for (int i = 0; i < 4; ++i)
#pragma unroll
                for (int j = 0; j < 4; ++j)
                    acc[i][j] = __builtin_amdgcn_mfma_f32_16x16x32_bf16(
                        af[i], bfr[j], acc[i][j], 0, 0, 0);
            __syncthreads();
        }
    }

    // ---- epilogue ----  C/D layout: col=lane&15, row=(lane>>4)*4+r
    const int ldo = 2048;
    const int ccol = lane & 15;
    const int crow = (lane >> 4) * 4;
#pragma unroll
    for (int i = 0; i < 4; ++i) {
#pragma unroll
        for (int j = 0; j < 4; ++j) {
            const int gr0 = bm * BM + wm + i * 16 + crow;
            const int gc = bn * BN + wn + j * 16 + ccol;
            float v[4];
#pragma unroll
            for (int r = 0; r < 4; ++r) {
                v[r] = acc[i][j][r];
                if (op.Add) v[r] += op.Add[(size_t)(gr0 + r) * ldo + gc];
            }
            if (op.OutB) {
#pragma unroll
                for (int r = 0; r < 4; ++r)
                    op.OutB[(size_t)(gr0 + r) * ldo + gc] = f32_to_bf16(v[r]);
            }
            if (op.OutT) {
                uint2 u;
                u.x = (uint32_t)f32_to_bf16(v[0]) | ((uint32_t)f32_to_bf16(v[1]) << 16);
                u.y = (uint32_t)f32_to_bf16(v[2]) | ((uint32_t)f32_to_bf16(v[3]) << 16);
                *(uint2*)(&op.OutT[(size_t)gc * ldo + gr0]) = u;   // gr0 % 4 == 0
            }
            if (op.OutF) {
#pragma unroll
                for (int r = 0; r < 4; ++r)
                    op.OutF[(size_t)(gr0 + r) * ldo + gc] = v[r];
            }
        }
    }
}

static inline GemmOp mkop(const u16* U, const u16* V, int K, int ldu, int ldv,
                          const float* Add, u16* OutB, u16* OutT, float* OutF) {
    GemmOp o;
    o.U = U; o.V = V; o.Add = Add; o.OutB = OutB; o.OutT = OutT; o.OutF = OutF;
    o.K = K; o.ldu = ldu; o.ldv = ldv;
    return o;
}

extern "C" void kernel_launch(void* const* d_in, const int* in_sizes, int n_in,
                              void* d_out, int out_size, void* d_ws, size_t ws_size,
                              hipStream_t stream) {
    const float* A = (const float*)d_in[0];     // (2048, 2048)
    const float* A_F = (const float*)d_in[1];   // (2048, 2048)
    const float* C = (const float*)d_in[2];     // (512, 2048)
    const float* C_F = (const float*)d_in[3];   // (512, 2048)
    const int n = 2048, p = 512;
    (void)in_sizes; (void)n_in; (void)out_size; (void)ws_size;

    char* ws = (char*)d_ws;
    const size_t MB = 1u << 20;
    // ---- Smith squaring, 6 levels -> S_64 (measured absmax 0.5; S_32 tail
    // bound was too loose to risk — see R5 post-mortem).
    u16* AT   = (u16*)(ws + 0 * MB);    // A^T  bf16  (A_0 transposed form)
    u16* Ab   = (u16*)(ws + 8 * MB);    // A    bf16  (A_0 row form)
    u16* AFT  = (u16*)(ws + 16 * MB);   // B=A_F^T row bf16 (B_0 row form)
    u16* AFb  = (u16*)(ws + 24 * MB);   // A_F  bf16  (B_0 transposed form)
    u16* CFT  = (u16*)(ws + 32 * MB);   // C_F^T bf16 (2048x512)
    u16* CT   = (u16*)(ws + 34 * MB);   // C^T   bf16 (2048x512)
    float* R32 = (float*)(ws + 36 * MB);// running R fp32
    u16* Rb   = (u16*)(ws + 52 * MB);   // running R bf16 row
    u16* XT   = (u16*)(ws + 60 * MB);   // (R*A_i)^T bf16
    u16* Tb1  = (u16*)(ws + 68 * MB);   // ping-pong set 1: B_i row
    u16* TbT1 = (u16*)(ws + 76 * MB);   //                  B_i^T
    u16* Ub1  = (u16*)(ws + 84 * MB);   //                  A_i row
    u16* UbT1 = (u16*)(ws + 92 * MB);   //                  A_i^T

    dim3 tb(32, 8);
    stein_transpose_f32_bf16<<<dim3(64, 64), tb, 0, stream>>>(A, AT, n, n);
    stein_convert_f32_bf16<<<4096, 256, 0, stream>>>(A, Ab, n * n);
    stein_transpose_f32_bf16<<<dim3(64, 64), tb, 0, stream>>>(A_F, AFT, n, n);
    stein_convert_f32_bf16<<<4096, 256, 0, stream>>>(A_F, AFb, n * n);
    stein_transpose_f32_bf16<<<dim3(64, 16), tb, 0, stream>>>(C_F, CFT, p, n);
    stein_transpose_f32_bf16<<<dim3(64, 16), tb, 0, stream>>>(C, CT, p, n);

    dim3 blk(256);
    // R_0 = C_F^T C  (fp32 + bf16 row)
    {
        GemmOp r0 = mkop(CFT, CT, p, p, p, nullptr, Rb, nullptr, R32);
        stein_gemm_nt2<<<dim3(16, 16, 1), blk, 0, stream>>>(r0, r0);
    }

    u16* Tb[2]  = {AFT, Tb1};
    u16* TbT[2] = {AFb, TbT1};
    u16* Ub[2]  = {Ab, Ub1};
    u16* UbT[2] = {AT, UbT1};

    for (int i = 0; i < 6; ++i) {
        const int c = i & 1, nx = c ^ 1;
        GemmOp oXT = mkop(Rb, UbT[c], n, n, n, nullptr, nullptr, XT, nullptr);
        if (i < 5) {
            GemmOp oBsq = mkop(Tb[c], TbT[c], n, n, n, nullptr, Tb[nx], TbT[nx], nullptr);
            stein_gemm_nt2<<<dim3(16, 16, 2), blk, 0, stream>>>(oXT, oBsq);
            GemmOp oRup = mkop(Tb[c], XT, n, n, n, R32, Rb, nullptr, R32);
            GemmOp oAsq = mkop(Ub[c], UbT[c], n, n, n, nullptr, Ub[nx], UbT[nx], nullptr);
            stein_gemm_nt2<<<dim3(16, 16, 2), blk, 0, stream>>>(oRup, oAsq);
        } else {
            stein_gemm_nt2<<<dim3(16, 16, 1), blk, 0, stream>>>(oXT, oXT);
            // final: S_64 = B_5 X + R -> fp32 d_out
            GemmOp oFin = mkop(Tb[c], XT, n, n, n, R32, nullptr, nullptr, (float*)d_out);
            stein_gemm_nt2<<<dim3(16, 16, 1), blk, 0, stream>>>(oFin, oFin);
        }
    }
}